// Round 2
// baseline (131.578 us; speedup 1.0000x reference)
//
#include <hip/hip_runtime.h>

// Problem constants (match reference)
#define BB 2
#define CC 128
#define NN 4096
#define MM 16384

// ---------------------------------------------------------------------------
// Exact-match kernel. Semantics: sel[b,m] = lowest index i with
// xyz[b,:,i] == anchor[b,:,m] (float equality, all 3 coords), else 0xFFFFFFFF.
// This equals the reference's argmin+exact-mask pipeline: a nonzero output
// requires NN coords == anchor coords exactly, and an exact-match point always
// wins the argmin (self-distance rounding ~1e-7 << min pairwise d^2 ~1e-4).
//
// grid = B*M/64 = 512 blocks, block = 256 (4 waves). Each block owns 64
// anchors; wave w scans point-quarter w. All 4096 points (x,y,z) staged in
// LDS (48KB). Fast path: 1 v_cmp_eq per point accumulated into a 64-bit
// ballot (s_or_b64 on the SALU pipe). Rare path (x-coord hit): rescan own
// quarter verifying all 3 coords, first index wins; LDS atomicMin combines
// quarters (lowest global index wins ties, matching jnp.argmin).
// ---------------------------------------------------------------------------
__global__ __launch_bounds__(256) void match_kernel(
    const float* __restrict__ xyz,      // [B,3,N]
    const float* __restrict__ anchor,   // [B,3,M]
    unsigned int* __restrict__ sel)     // [B*M]
{
    __shared__ float xs[NN];
    __shared__ float ys[NN];
    __shared__ float zs[NN];
    __shared__ unsigned int best[64];

    const int g    = blockIdx.x;        // 0..511
    const int b    = g >> 8;            // 256 anchor-groups per batch
    const int m0   = (g & 255) * 64;
    const int t    = threadIdx.x;
    const int lane = t & 63;
    const int w    = t >> 6;            // wave id = point quarter

    // stage all N points (coalesced float4)
    const float* xb = xyz + b * 3 * NN;
    #pragma unroll
    for (int k = 0; k < NN / 4 / 256; ++k) {
        int idx = k * 256 + t;
        ((float4*)xs)[idx] = ((const float4*)xb)[idx];
        ((float4*)ys)[idx] = ((const float4*)(xb + NN))[idx];
        ((float4*)zs)[idx] = ((const float4*)(xb + 2 * NN))[idx];
    }
    if (t < 64) best[t] = 0xFFFFFFFFu;
    __syncthreads();

    const int m = m0 + lane;
    const float* ap = anchor + b * 3 * MM;
    const float a0 = ap[m];
    const float a1 = ap[MM + m];
    const float a2 = ap[2 * MM + m];

    // fast scan: x-coordinate equality only, 1 VALU cmp per point
    const int i0 = w * (NN / 4);
    unsigned long long acc = 0ull;
    #pragma unroll 4
    for (int i = 0; i < NN / 4; i += 4) {
        float4 p = ((const float4*)xs)[(i0 + i) >> 2];  // wave-uniform -> broadcast
        acc |= __ballot(p.x == a0);
        acc |= __ballot(p.y == a0);   // p.y/p.z/p.w are the next 3 x-coords
        acc |= __ballot(p.z == a0);
        acc |= __ballot(p.w == a0);
    }

    // rare path: this lane's anchor had an x-coordinate hit in this quarter
    if ((acc >> lane) & 1ull) {
        unsigned int bi = 0xFFFFFFFFu;
        for (int i = i0; i < i0 + NN / 4; ++i) {
            if (xs[i] == a0 && ys[i] == a1 && zs[i] == a2) { bi = (unsigned)i; break; }
        }
        if (bi != 0xFFFFFFFFu) atomicMin(&best[lane], bi);
    }
    __syncthreads();
    if (t < 64) sel[(size_t)b * MM + m0 + t] = best[t];
}

// ---------------------------------------------------------------------------
// Gather: one thread per 4 elements of out1 [B,C,M] (float4 stores).
// ---------------------------------------------------------------------------
__global__ __launch_bounds__(256) void gather_kernel(
    const float* __restrict__ feature,      // [B,C,N]
    const unsigned int* __restrict__ sel,   // [B*M]
    float* __restrict__ out1)               // [B,C,M]
{
    const int q = blockIdx.x * 256 + threadIdx.x;    // quad index < B*C*M/4
    const int o = q * 4;
    const int m = o & (MM - 1);
    const int c = (o >> 14) & (CC - 1);              // M = 2^14
    const int b = o >> 21;                           // C*M = 2^21
    uint4 s4 = ((const uint4*)(sel + (size_t)b * MM))[m >> 2];
    const float* frow = feature + ((size_t)(b * CC + c)) * NN;
    float4 v;
    v.x = (s4.x < NN) ? frow[s4.x] : 0.0f;
    v.y = (s4.y < NN) ? frow[s4.y] : 0.0f;
    v.z = (s4.z < NN) ? frow[s4.z] : 0.0f;
    v.w = (s4.w < NN) ? frow[s4.w] : 0.0f;
    ((float4*)out1)[q] = v;
}

extern "C" void kernel_launch(void* const* d_in, const int* in_sizes, int n_in,
                              void* d_out, int out_size, void* d_ws, size_t ws_size,
                              hipStream_t stream) {
    const float* xyz    = (const float*)d_in[0];  // [B,3,N]
    const float* feat   = (const float*)d_in[1];  // [B,C,N]
    const float* anchor = (const float*)d_in[2];  // [B,3,M]

    float* out0 = (float*)d_out;                  // [B,3,M] passthrough
    float* out1 = out0 + BB * 3 * MM;             // [B,C,M]

    unsigned int* sel = (unsigned int*)d_ws;      // [B*M] u32

    // output 0: exact passthrough of xyz_anchor
    hipMemcpyAsync(out0, anchor, (size_t)BB * 3 * MM * sizeof(float),
                   hipMemcpyDeviceToDevice, stream);

    match_kernel<<<BB * MM / 64, 256, 0, stream>>>(xyz, anchor, sel);
    gather_kernel<<<BB * CC * MM / 4 / 256, 256, 0, stream>>>(feat, sel, out1);
}

// Round 3
// 36.658 us; speedup vs baseline: 3.5894x; 3.5894x over previous
//
#include <hip/hip_runtime.h>

// Problem constants (match reference)
#define BB 2
#define CC 128
#define NN 4096
#define MM 16384
#define TS 8192            // hash slots per batch (pow2, load factor 0.5)
#define EMPTYV 0xFFFFFFFFu

// Canonicalize -0.0f -> +0.0f so float== equivalence classes hash identically.
__device__ __forceinline__ unsigned cbits(float v) {
    return __float_as_uint(v == 0.0f ? 0.0f : v);
}
__device__ __forceinline__ unsigned hash3(float x, float y, float z) {
    unsigned h = cbits(x) * 0x9E3779B1u;
    h ^= cbits(y) * 0x85EBCA77u;
    h ^= cbits(z) * 0xC2B2AE3Du;
    h ^= h >> 16;  h *= 0x7FEB352Du;  h ^= h >> 15;
    return h;
}

// ---------------------------------------------------------------------------
// Build: insert each source point into the per-batch table. Open addressing,
// linear probe. Slot holds the LOWEST index of its coordinate class
// (atomicMin on duplicate coords -> matches jnp.argmin first-index tie-break).
// ---------------------------------------------------------------------------
__global__ __launch_bounds__(256) void build_kernel(
    const float* __restrict__ xyz,       // [B,3,N]
    unsigned* __restrict__ tab)          // [B,TS], pre-memset to 0xFF
{
    const int i = blockIdx.x * 256 + threadIdx.x;   // < B*N
    const int b = i >> 12;                          // N = 2^12
    const int n = i & (NN - 1);
    const float* xb = xyz + b * 3 * NN;
    const float x = xb[n], y = xb[NN + n], z = xb[2 * NN + n];
    unsigned* t = tab + b * TS;
    unsigned slot = hash3(x, y, z) & (TS - 1);
    while (true) {
        unsigned old = atomicCAS(&t[slot], EMPTYV, (unsigned)n);
        if (old == EMPTYV) break;                    // claimed empty slot
        if (xb[old] == x && xb[NN + old] == y && xb[2 * NN + old] == z) {
            atomicMin(&t[slot], (unsigned)n);        // duplicate coords: keep min idx
            break;
        }
        slot = (slot + 1) & (TS - 1);
    }
}

// ---------------------------------------------------------------------------
// Lookup: each anchor probes the table; on candidate, verify all 3 coords
// with float== (handles +-0 across classes). sel = index or 0xFFFFFFFF.
// ---------------------------------------------------------------------------
__global__ __launch_bounds__(256) void lookup_kernel(
    const float* __restrict__ xyz,       // [B,3,N]
    const float* __restrict__ anchor,    // [B,3,M]
    const unsigned* __restrict__ tab,    // [B,TS]
    unsigned* __restrict__ sel)          // [B*M]
{
    const int i = blockIdx.x * 256 + threadIdx.x;   // < B*M
    const int b = i >> 14;                          // M = 2^14
    const int m = i & (MM - 1);
    const float* ap = anchor + b * 3 * MM;
    const float a0 = ap[m], a1 = ap[MM + m], a2 = ap[2 * MM + m];
    const float* xb = xyz + b * 3 * NN;
    const unsigned* t = tab + b * TS;
    unsigned slot = hash3(a0, a1, a2) & (TS - 1);
    unsigned res = EMPTYV;
    while (true) {
        unsigned v = t[slot];
        if (v == EMPTYV) break;                      // no exact match exists
        if (xb[v] == a0 && xb[NN + v] == a1 && xb[2 * NN + v] == a2) { res = v; break; }
        slot = (slot + 1) & (TS - 1);
    }
    sel[i] = res;
}

// ---------------------------------------------------------------------------
// Gather: one thread per 4 elements of out1 [B,C,M] (float4 stores).
// ---------------------------------------------------------------------------
__global__ __launch_bounds__(256) void gather_kernel(
    const float* __restrict__ feature,      // [B,C,N]
    const unsigned* __restrict__ sel,       // [B*M]
    float* __restrict__ out1)               // [B,C,M]
{
    const int q = blockIdx.x * 256 + threadIdx.x;    // quad index < B*C*M/4
    const int o = q * 4;
    const int m = o & (MM - 1);
    const int c = (o >> 14) & (CC - 1);              // M = 2^14
    const int b = o >> 21;                           // C*M = 2^21
    uint4 s4 = ((const uint4*)(sel + (size_t)b * MM))[m >> 2];
    const float* frow = feature + ((size_t)(b * CC + c)) * NN;
    float4 v;
    v.x = (s4.x < NN) ? frow[s4.x] : 0.0f;
    v.y = (s4.y < NN) ? frow[s4.y] : 0.0f;
    v.z = (s4.z < NN) ? frow[s4.z] : 0.0f;
    v.w = (s4.w < NN) ? frow[s4.w] : 0.0f;
    ((float4*)out1)[q] = v;
}

extern "C" void kernel_launch(void* const* d_in, const int* in_sizes, int n_in,
                              void* d_out, int out_size, void* d_ws, size_t ws_size,
                              hipStream_t stream) {
    const float* xyz    = (const float*)d_in[0];  // [B,3,N]
    const float* feat   = (const float*)d_in[1];  // [B,C,N]
    const float* anchor = (const float*)d_in[2];  // [B,3,M]

    float* out0 = (float*)d_out;                  // [B,3,M] passthrough
    float* out1 = out0 + BB * 3 * MM;             // [B,C,M]

    // workspace: tab (B*TS u32) | sel (B*M u32)
    unsigned* tab = (unsigned*)d_ws;
    unsigned* sel = tab + BB * TS;

    // output 0: exact passthrough of xyz_anchor (concurrent with table build)
    hipMemcpyAsync(out0, anchor, (size_t)BB * 3 * MM * sizeof(float),
                   hipMemcpyDeviceToDevice, stream);

    hipMemsetAsync(tab, 0xFF, (size_t)BB * TS * sizeof(unsigned), stream);
    build_kernel<<<BB * NN / 256, 256, 0, stream>>>(xyz, tab);
    lookup_kernel<<<BB * MM / 256, 256, 0, stream>>>(xyz, anchor, tab, sel);
    gather_kernel<<<BB * CC * MM / 4 / 256, 256, 0, stream>>>(feat, sel, out1);
}

// Round 4
// 29.289 us; speedup vs baseline: 4.4924x; 1.2516x over previous
//
#include <hip/hip_runtime.h>

// Problem constants (match reference)
#define BB 2
#define CC 128
#define NN 4096
#define MM 16384
#define TS 8192            // hash slots (pow2, load factor 0.5) -> 32KB LDS
#define APB 128            // anchors per block
#define THREADS 512
#define EMPTYV 0xFFFFFFFFu

// Canonicalize -0.0f -> +0.0f so float== equivalence classes hash identically.
__device__ __forceinline__ unsigned cbits(float v) {
    return __float_as_uint(v == 0.0f ? 0.0f : v);
}
__device__ __forceinline__ unsigned hash3(float x, float y, float z) {
    unsigned h = cbits(x) * 0x9E3779B1u;
    h ^= cbits(y) * 0x85EBCA77u;
    h ^= cbits(z) * 0xC2B2AE3Du;
    h ^= h >> 16;  h *= 0x7FEB352Du;  h ^= h >> 15;
    return h;
}

// ---------------------------------------------------------------------------
// Fully fused: per block (256 blocks = B * M/APB), build the batch's exact-
// match hash table REDUNDANTLY in LDS (no global table, no memset, no
// cross-block deps), look up this block's APB anchors, then gather+store the
// APB x CC output slice. Also copies the xyz_anchor passthrough slice.
// Semantics (validated absmax=0 in R1-R3): sel[b,m] = lowest i with
// xyz[b,:,i] == anchor[b,:,m] (float ==), else none -> zeros.
// ---------------------------------------------------------------------------
__global__ __launch_bounds__(THREADS) void fused_kernel(
    const float* __restrict__ xyz,       // [B,3,N]
    const float* __restrict__ feature,   // [B,C,N]
    const float* __restrict__ anchor,    // [B,3,M]
    float* __restrict__ out0,            // [B,3,M]
    float* __restrict__ out1)            // [B,C,M]
{
    __shared__ unsigned tab[TS];
    __shared__ unsigned sel[APB];

    const int blk = blockIdx.x;
    const int b   = blk / (MM / APB);            // 128 blocks per batch
    const int m0  = (blk % (MM / APB)) * APB;
    const int t   = threadIdx.x;

    // ---- clear LDS table (uint4 stores) ----
    #pragma unroll
    for (int k = 0; k < TS / 4 / THREADS; ++k)
        ((uint4*)tab)[k * THREADS + t] = make_uint4(EMPTYV, EMPTYV, EMPTYV, EMPTYV);

    // ---- passthrough: out0 slice = anchor slice (3*APB floats = 96 float4) ----
    const float* ap = anchor + (size_t)b * 3 * MM;
    if (t < 3 * APB / 4) {
        int d = t >> 5, i = t & 31;              // 3 rows x 32 float4
        ((float4*)(out0 + (size_t)b * 3 * MM + (size_t)d * MM + m0))[i] =
            ((const float4*)(ap + (size_t)d * MM + m0))[i];
    }
    __syncthreads();

    // ---- build: insert all N batch points (NN/THREADS = 8 per thread) ----
    // Slot keeps the LOWEST index of its coord class (atomicMin on duplicate
    // coords -> matches jnp.argmin first-index tie-break).
    const float* xb = xyz + (size_t)b * 3 * NN;
    #pragma unroll
    for (int k = 0; k < NN / THREADS; ++k) {
        int n = k * THREADS + t;
        float x = xb[n], y = xb[NN + n], z = xb[2 * NN + n];
        unsigned slot = hash3(x, y, z) & (TS - 1);
        while (true) {
            unsigned old = atomicCAS(&tab[slot], EMPTYV, (unsigned)n);
            if (old == EMPTYV) break;
            if (xb[old] == x && xb[NN + old] == y && xb[2 * NN + old] == z) {
                atomicMin(&tab[slot], (unsigned)n);
                break;
            }
            slot = (slot + 1) & (TS - 1);
        }
    }
    __syncthreads();

    // ---- lookup this block's APB anchors ----
    if (t < APB) {
        int m = m0 + t;
        float a0 = ap[m], a1 = ap[MM + m], a2 = ap[2 * MM + m];
        unsigned slot = hash3(a0, a1, a2) & (TS - 1);
        unsigned res = EMPTYV;
        while (true) {
            unsigned v = tab[slot];
            if (v == EMPTYV) break;
            if (xb[v] == a0 && xb[NN + v] == a1 && xb[2 * NN + v] == a2) { res = v; break; }
            slot = (slot + 1) & (TS - 1);
        }
        sel[t] = res;
    }
    __syncthreads();

    // ---- gather: APB/4 = 32 quads x CC channels, float4 stores ----
    const float* fb = feature + (size_t)b * CC * NN;
    float* ob = out1 + (size_t)b * CC * MM + m0;
    const int q  = t & 31;                       // m-quad within block
    const int c0 = t >> 5;                       // 0..15
    uint4 s4 = ((uint4*)sel)[q];
    #pragma unroll
    for (int k = 0; k < CC * 32 / THREADS; ++k) {   // 8 iterations
        int c = c0 + k * (THREADS / 32);
        const float* frow = fb + (size_t)c * NN;
        float4 v;
        v.x = (s4.x < NN) ? frow[s4.x] : 0.0f;
        v.y = (s4.y < NN) ? frow[s4.y] : 0.0f;
        v.z = (s4.z < NN) ? frow[s4.z] : 0.0f;
        v.w = (s4.w < NN) ? frow[s4.w] : 0.0f;
        ((float4*)(ob + (size_t)c * MM))[q] = v;
    }
}

extern "C" void kernel_launch(void* const* d_in, const int* in_sizes, int n_in,
                              void* d_out, int out_size, void* d_ws, size_t ws_size,
                              hipStream_t stream) {
    const float* xyz    = (const float*)d_in[0];  // [B,3,N]
    const float* feat   = (const float*)d_in[1];  // [B,C,N]
    const float* anchor = (const float*)d_in[2];  // [B,3,M]

    float* out0 = (float*)d_out;                  // [B,3,M] passthrough
    float* out1 = out0 + BB * 3 * MM;             // [B,C,M]

    fused_kernel<<<BB * (MM / APB), THREADS, 0, stream>>>(xyz, feat, anchor, out0, out1);
}

// Round 5
// 27.862 us; speedup vs baseline: 4.7225x; 1.0512x over previous
//
#include <hip/hip_runtime.h>

// Problem constants (match reference)
#define BB 2
#define CC 128
#define NN 4096
#define MM 16384
#define TS 8192            // hash slots per batch (pow2, load 0.5) -> 32KB
#define EMPTYV 0xFFFFFFFFu

// Canonicalize -0.0f -> +0.0f so float== equivalence classes hash identically.
__device__ __forceinline__ unsigned cbits(float v) {
    return __float_as_uint(v == 0.0f ? 0.0f : v);
}
__device__ __forceinline__ unsigned hash3(float x, float y, float z) {
    unsigned h = cbits(x) * 0x9E3779B1u;
    h ^= cbits(y) * 0x85EBCA77u;
    h ^= cbits(z) * 0xC2B2AE3Du;
    h ^= h >> 16;  h *= 0x7FEB352Du;  h ^= h >> 15;
    return h;
}

// ---------------------------------------------------------------------------
// K1: one block per batch. Build the exact-match table in LDS (block-private,
// LDS atomics), then dump 32KB coalesced to the global table in ws.
// Slot keeps LOWEST index of its float== coordinate class (atomicMin on
// duplicates -> matches jnp.argmin first-index tie-break). Final table state
// is deterministic (min index per class; probe-chain property of linear
// probing holds under any insertion interleaving since there are no deletes).
// ---------------------------------------------------------------------------
__global__ __launch_bounds__(1024) void build_kernel(
    const float* __restrict__ xyz,       // [B,3,N]
    unsigned* __restrict__ tab)          // [B,TS]
{
    __shared__ unsigned ltab[TS];
    const int b = blockIdx.x;
    const int t = threadIdx.x;

    #pragma unroll
    for (int k = 0; k < TS / 4 / 1024; ++k)   // 2 uint4 per thread
        ((uint4*)ltab)[k * 1024 + t] = make_uint4(EMPTYV, EMPTYV, EMPTYV, EMPTYV);
    __syncthreads();

    const float* xb = xyz + (size_t)b * 3 * NN;
    #pragma unroll
    for (int k = 0; k < NN / 1024; ++k) {     // 4 inserts per thread
        int n = k * 1024 + t;
        float x = xb[n], y = xb[NN + n], z = xb[2 * NN + n];
        unsigned slot = hash3(x, y, z) & (TS - 1);
        while (true) {
            unsigned old = atomicCAS(&ltab[slot], EMPTYV, (unsigned)n);
            if (old == EMPTYV) break;
            if (xb[old] == x && xb[NN + old] == y && xb[2 * NN + old] == z) {
                atomicMin(&ltab[slot], (unsigned)n);
                break;
            }
            slot = (slot + 1) & (TS - 1);
        }
    }
    __syncthreads();

    #pragma unroll
    for (int k = 0; k < TS / 4 / 1024; ++k)
        ((uint4*)(tab + (size_t)b * TS))[k * 1024 + t] = ((uint4*)ltab)[k * 1024 + t];
}

// ---------------------------------------------------------------------------
// K2: 2048 blocks x 256 threads, 16 anchors per block. Threads 0-15 probe the
// L2-resident table + verify coords (float ==); threads 64-75 copy the
// xyz_anchor passthrough slice; after sync all 256 threads stream the
// [CC x 16] output tile with float4 stores. No big LDS -> 8 blocks/CU,
// lookup latency hidden by co-resident blocks' stores.
// ---------------------------------------------------------------------------
__global__ __launch_bounds__(256) void lookup_gather_kernel(
    const float* __restrict__ xyz,       // [B,3,N]
    const float* __restrict__ feature,   // [B,C,N]
    const float* __restrict__ anchor,    // [B,3,M]
    const unsigned* __restrict__ tab,    // [B,TS]
    float* __restrict__ out0,            // [B,3,M]
    float* __restrict__ out1)            // [B,C,M]
{
    __shared__ unsigned sel[16];

    const int blk = blockIdx.x;
    const int b   = blk >> 10;               // M/16 = 1024 blocks per batch
    const int m0  = (blk & 1023) * 16;
    const int t   = threadIdx.x;

    const float* ap = anchor + (size_t)b * 3 * MM;
    const float* xb = xyz + (size_t)b * 3 * NN;

    if (t < 16) {
        int m = m0 + t;
        float a0 = ap[m], a1 = ap[MM + m], a2 = ap[2 * MM + m];
        const unsigned* tb = tab + (size_t)b * TS;
        unsigned slot = hash3(a0, a1, a2) & (TS - 1);
        unsigned res = EMPTYV;
        while (true) {
            unsigned v = tb[slot];
            if (v == EMPTYV) break;          // no exact match exists
            if (xb[v] == a0 && xb[NN + v] == a1 && xb[2 * NN + v] == a2) { res = v; break; }
            slot = (slot + 1) & (TS - 1);
        }
        sel[t] = res;
    } else if (t >= 64 && t < 76) {
        // passthrough: 3 rows x 4 float4 of this block's anchor slice
        int d = (t - 64) >> 2, i = (t - 64) & 3;
        ((float4*)(out0 + (size_t)b * 3 * MM + (size_t)d * MM + m0))[i] =
            ((const float4*)(ap + (size_t)d * MM + m0))[i];
    }
    __syncthreads();

    // gather: tile [CC rows x 16 m] = 512 float4; 2 per thread
    const float* fb = feature + (size_t)b * CC * NN;
    float* ob = out1 + (size_t)b * CC * MM + m0;
    const int q  = t & 3;                    // float4-quad within row
    const int c0 = t >> 2;                   // 0..63
    uint4 s4 = ((uint4*)sel)[q];
    #pragma unroll
    for (int k = 0; k < 2; ++k) {
        int c = c0 + k * 64;
        const float* frow = fb + (size_t)c * NN;
        float4 v;
        v.x = (s4.x < NN) ? frow[s4.x] : 0.0f;
        v.y = (s4.y < NN) ? frow[s4.y] : 0.0f;
        v.z = (s4.z < NN) ? frow[s4.z] : 0.0f;
        v.w = (s4.w < NN) ? frow[s4.w] : 0.0f;
        ((float4*)(ob + (size_t)c * MM))[q] = v;
    }
}

extern "C" void kernel_launch(void* const* d_in, const int* in_sizes, int n_in,
                              void* d_out, int out_size, void* d_ws, size_t ws_size,
                              hipStream_t stream) {
    const float* xyz    = (const float*)d_in[0];  // [B,3,N]
    const float* feat   = (const float*)d_in[1];  // [B,C,N]
    const float* anchor = (const float*)d_in[2];  // [B,3,M]

    float* out0 = (float*)d_out;                  // [B,3,M] passthrough
    float* out1 = out0 + BB * 3 * MM;             // [B,C,M]

    unsigned* tab = (unsigned*)d_ws;              // [B,TS]

    build_kernel<<<BB, 1024, 0, stream>>>(xyz, tab);
    lookup_gather_kernel<<<BB * MM / 16, 256, 0, stream>>>(xyz, feat, anchor, tab, out0, out1);
}